// Round 1
// baseline (227.138 us; speedup 1.0000x reference)
//
#include <hip/hip_runtime.h>
#include <hip/hip_bf16.h>
#include <stdint.h>

typedef __attribute__((ext_vector_type(4))) float f32x4;
typedef __attribute__((ext_vector_type(8))) short bf16x8;

#define ATT_SCALE 0.125f   // 64^-0.5

__device__ inline short f2bf(float f) {
  unsigned u = __builtin_bit_cast(unsigned, f);
  u += 0x7fffu + ((u >> 16) & 1u);   // RNE
  return (short)(u >> 16);
}

__device__ inline void gload_lds16(const void* g, void* l) {
  __builtin_amdgcn_global_load_lds(
      (const __attribute__((address_space(1))) void*)g,
      (__attribute__((address_space(3))) void*)l, 16, 0, 0);
}

// ---------------- fp32 -> bf16 convert (vectorized) ----------------
__global__ __launch_bounds__(256) void cvt_bf16(const float* __restrict__ src,
                                                short* __restrict__ dst, int n8) {
  int i = blockIdx.x * 256 + threadIdx.x;
  if (i >= n8) return;
  const float4* s = (const float4*)src;
  float4 a = s[2 * i], b = s[2 * i + 1];
  bf16x8 o;
  o[0] = f2bf(a.x); o[1] = f2bf(a.y); o[2] = f2bf(a.z); o[3] = f2bf(a.w);
  o[4] = f2bf(b.x); o[5] = f2bf(b.y); o[6] = f2bf(b.z); o[7] = f2bf(b.w);
  ((bf16x8*)dst)[i] = o;
}

// ---------------- m97-style GEMM: C[M][N] = A[M][K] * B[N][K]^T ----------------
// A,B bf16 row-major (K contiguous). F32OUT=1: fp32 out + bias; else bf16 out.
template <int F32OUT>
__global__ __launch_bounds__(256) void gemm_bt(const short* __restrict__ A,
                                               const short* __restrict__ B,
                                               void* __restrict__ Cv,
                                               const float* __restrict__ bias,
                                               int M, int N, int K) {
  __shared__ short As[128 * 64];
  __shared__ short Bs[128 * 64];
  const int tid = threadIdx.x, wv = tid >> 6, ln = tid & 63;
  const int wm = wv >> 1, wn = wv & 1;
  const int bm0 = blockIdx.y * 128, bn0 = blockIdx.x * 128;
  const int lrow = ln & 15, lk = (ln >> 4) * 8;
  f32x4 acc[4][4] = {};

  for (int k0 = 0; k0 < K; k0 += 64) {
    __syncthreads();
#pragma unroll
    for (int i = 0; i < 4; i++) {
      int id = i * 256 + tid;
      int row = id >> 3, col = (id & 7) * 8;
      gload_lds16(A + (size_t)(bm0 + row) * K + k0 + col,
                  (char*)As + (i * 4 + wv) * 1024);
      gload_lds16(B + (size_t)(bn0 + row) * K + k0 + col,
                  (char*)Bs + (i * 4 + wv) * 1024);
    }
    __syncthreads();
#pragma unroll
    for (int kk = 0; kk < 2; kk++) {
      bf16x8 af[4], bfr[4];
#pragma unroll
      for (int m = 0; m < 4; m++)
        af[m] = *(const bf16x8*)&As[(wm * 64 + m * 16 + lrow) * 64 + kk * 32 + lk];
#pragma unroll
      for (int n = 0; n < 4; n++)
        bfr[n] = *(const bf16x8*)&Bs[(wn * 64 + n * 16 + lrow) * 64 + kk * 32 + lk];
#pragma unroll
      for (int m = 0; m < 4; m++)
#pragma unroll
        for (int n = 0; n < 4; n++)
          acc[m][n] = __builtin_amdgcn_mfma_f32_16x16x32_bf16(af[m], bfr[n], acc[m][n], 0, 0, 0);
    }
  }

  const int r0 = bm0 + wm * 64, c0 = bn0 + wn * 64;
#pragma unroll
  for (int m = 0; m < 4; m++)
#pragma unroll
    for (int n = 0; n < 4; n++)
#pragma unroll
      for (int r = 0; r < 4; r++) {
        int row = r0 + m * 16 + (ln >> 4) * 4 + r;
        int col = c0 + n * 16 + lrow;
        if (F32OUT) {
          ((float*)Cv)[(size_t)row * N + col] = acc[m][n][r] + bias[col];
        } else {
          ((short*)Cv)[(size_t)row * N + col] = f2bf(acc[m][n][r]);
        }
      }
}

// ---------------- flash attention ----------------
// QKV: [B*N=4096][3072] bf16 rows; q at f=h*64+d, k at +1024, v at +2048.
// Grid: (32 q-tiles, 32 bh). Block: 256 thr = 4 waves, wave handles 16 q-rows.
__global__ __launch_bounds__(256) void attn_fwd(const short* __restrict__ QKV,
                                                short* __restrict__ AO) {
  __shared__ short Qs[64 * 64];
  __shared__ short Ks[64 * 64];
  __shared__ short Vt[64 * 64];      // transposed: [d][kv]
  __shared__ short Ps[4 * 16 * 64];  // per-wave P tile
  const int tid = threadIdx.x, wv = tid >> 6, ln = tid & 63;
  const int qt = blockIdx.x, bh = blockIdx.y;
  const int b = bh >> 4, h = bh & 15;
  const short* base = QKV + (size_t)b * 2048 * 3072 + h * 64;
  const short* Qg = base;
  const short* Kg = base + 1024;
  const short* Vg = base + 2048;
  const int lrow = ln & 15, lk = (ln >> 4) * 8;

  // stage Q tile [64][64], swizzled
#pragma unroll
  for (int i = 0; i < 2; i++) {
    int id = i * 256 + tid;
    int row = id >> 3, col = (id & 7) * 8;
    bf16x8 v = *(const bf16x8*)(Qg + (size_t)(qt * 64 + row) * 3072 + col);
    int byte = (row * 128 + col * 2) ^ ((row & 7) << 4);
    *(bf16x8*)((char*)Qs + byte) = v;
  }

  float m_run[4], l_run[4];
  f32x4 oacc[4] = {};
#pragma unroll
  for (int r = 0; r < 4; r++) { m_run[r] = -1e30f; l_run[r] = 0.f; }

  for (int t = 0; t < 32; t++) {
    // stage K tile [64][64], swizzled
#pragma unroll
    for (int i = 0; i < 2; i++) {
      int id = i * 256 + tid;
      int row = id >> 3, col = (id & 7) * 8;
      bf16x8 v = *(const bf16x8*)(Kg + (size_t)(t * 64 + row) * 3072 + col);
      int byte = (row * 128 + col * 2) ^ ((row & 7) << 4);
      *(bf16x8*)((char*)Ks + byte) = v;
    }
    // stage V transposed: lane = d column, wave covers 16 kv rows (coalesced 2B loads)
    {
      const int d = ln;
      const int kvh = wv * 16;
      unsigned short u[16];
#pragma unroll
      for (int i = 0; i < 16; i++)
        u[i] = *(const unsigned short*)(Vg + (size_t)(t * 64 + kvh + i) * 3072 + d);
      bf16x8 w0, w1;
#pragma unroll
      for (int i = 0; i < 8; i++) { w0[i] = (short)u[i]; w1[i] = (short)u[8 + i]; }
      int b0 = d * 128 + kvh * 2;
      *(bf16x8*)((char*)Vt + (b0 ^ ((d & 7) << 4))) = w0;
      *(bf16x8*)((char*)Vt + ((b0 + 16) ^ ((d & 7) << 4))) = w1;
    }
    __syncthreads();

    // S = Q K^T  (per wave: 16 q-rows x 64 kv)
    f32x4 sac[4] = {};
#pragma unroll
    for (int kk = 0; kk < 2; kk++) {
      int qbyte = ((wv * 16 + lrow) * 128 + (kk * 32 + lk) * 2) ^ ((lrow & 7) << 4);
      bf16x8 qa = *(const bf16x8*)((char*)Qs + qbyte);
#pragma unroll
      for (int n = 0; n < 4; n++) {
        int kbyte = ((n * 16 + lrow) * 128 + (kk * 32 + lk) * 2) ^ ((lrow & 7) << 4);
        bf16x8 kb = *(const bf16x8*)((char*)Ks + kbyte);
        sac[n] = __builtin_amdgcn_mfma_f32_16x16x32_bf16(qa, kb, sac[n], 0, 0, 0);
      }
    }

    // online softmax (rows = (ln>>4)*4+r, reduce over lane&15 x 4 frags)
    float pt[4][4], al[4];
#pragma unroll
    for (int r = 0; r < 4; r++) {
      float mx = fmaxf(fmaxf(sac[0][r], sac[1][r]), fmaxf(sac[2][r], sac[3][r])) * ATT_SCALE;
      mx = fmaxf(mx, __shfl_xor(mx, 1));
      mx = fmaxf(mx, __shfl_xor(mx, 2));
      mx = fmaxf(mx, __shfl_xor(mx, 4));
      mx = fmaxf(mx, __shfl_xor(mx, 8));
      float mn = fmaxf(m_run[r], mx);
      al[r] = __expf(m_run[r] - mn);
      m_run[r] = mn;
      float s = 0.f;
#pragma unroll
      for (int n = 0; n < 4; n++) {
        float p = __expf(sac[n][r] * ATT_SCALE - mn);
        pt[n][r] = p;
        s += p;
      }
      s += __shfl_xor(s, 1);
      s += __shfl_xor(s, 2);
      s += __shfl_xor(s, 4);
      s += __shfl_xor(s, 8);
      l_run[r] = l_run[r] * al[r] + s;
    }
#pragma unroll
    for (int n = 0; n < 4; n++)
#pragma unroll
      for (int r = 0; r < 4; r++) oacc[n][r] *= al[r];

    // P -> per-wave LDS (swizzled), then PV
#pragma unroll
    for (int n = 0; n < 4; n++)
#pragma unroll
      for (int r = 0; r < 4; r++) {
        int prow = (ln >> 4) * 4 + r, pcol = n * 16 + lrow;
        int byte = wv * 2048 + ((prow * 128 + pcol * 2) ^ ((prow & 7) << 4));
        *(short*)((char*)Ps + byte) = f2bf(pt[n][r]);
      }
    asm volatile("s_waitcnt lgkmcnt(0)" ::: "memory");

#pragma unroll
    for (int kk = 0; kk < 2; kk++) {
      int pbyte = wv * 2048 + ((lrow * 128 + (kk * 32 + lk) * 2) ^ ((lrow & 7) << 4));
      bf16x8 pa = *(const bf16x8*)((char*)Ps + pbyte);
#pragma unroll
      for (int n = 0; n < 4; n++) {
        int vbyte = ((n * 16 + lrow) * 128 + (kk * 32 + lk) * 2) ^ ((lrow & 7) << 4);
        bf16x8 vb = *(const bf16x8*)((char*)Vt + vbyte);
        oacc[n] = __builtin_amdgcn_mfma_f32_16x16x32_bf16(pa, vb, oacc[n], 0, 0, 0);
      }
    }
    __syncthreads();
  }

  // epilogue: AO[b, q, h, d] = O / l
#pragma unroll
  for (int n = 0; n < 4; n++)
#pragma unroll
    for (int r = 0; r < 4; r++) {
      int q = qt * 64 + wv * 16 + (ln >> 4) * 4 + r;
      int col = n * 16 + lrow;
      AO[((size_t)b * 2048 + q) * 1024 + h * 64 + col] = f2bf(oacc[n][r] / l_run[r]);
    }
}

// ---------------- launch ----------------
extern "C" void kernel_launch(void* const* d_in, const int* in_sizes, int n_in,
                              void* d_out, int out_size, void* d_ws, size_t ws_size,
                              hipStream_t stream) {
  const float* x = (const float*)d_in[0];       // [2,2048,1024]
  const float* w_qkv = (const float*)d_in[1];   // [3072,1024]
  const float* w_proj = (const float*)d_in[2];  // [1024,1024]
  const float* b_proj = (const float*)d_in[3];  // [1024]
  float* out = (float*)d_out;                   // [2,2048,1024] fp32

  char* ws = (char*)d_ws;
  short* Xb = (short*)(ws + 0);                  //  8 MB  [4096][1024]
  short* Wq = (short*)(ws + 8388608);            //  6 MB  [3072][1024]
  short* Wp = (short*)(ws + 14680064);           //  2 MB  [1024][1024]
  short* QKV = (short*)(ws + 16777216);          // 24 MB  [4096][3072]
  short* AO = (short*)(ws + 41943040);           //  8 MB  [4096][1024]

  cvt_bf16<<<2048, 256, 0, stream>>>(x, Xb, 4096 * 1024 / 8);
  cvt_bf16<<<1536, 256, 0, stream>>>(w_qkv, Wq, 3072 * 1024 / 8);
  cvt_bf16<<<512, 256, 0, stream>>>(w_proj, Wp, 1024 * 1024 / 8);

  gemm_bt<0><<<dim3(24, 32), 256, 0, stream>>>(Xb, Wq, (void*)QKV, nullptr, 4096, 3072, 1024);

  attn_fwd<<<dim3(32, 32), 256, 0, stream>>>(QKV, AO);

  gemm_bt<1><<<dim3(8, 32), 256, 0, stream>>>(AO, Wp, (void*)out, b_proj, 4096, 1024, 1024);
}

// Round 2
// 147.576 us; speedup vs baseline: 1.5391x; 1.5391x over previous
//
#include <hip/hip_runtime.h>
#include <hip/hip_bf16.h>
#include <stdint.h>

typedef __attribute__((ext_vector_type(4))) float f32x4;
typedef __attribute__((ext_vector_type(16))) float f32x16;
typedef __attribute__((ext_vector_type(8))) short bf16x8;
typedef __attribute__((ext_vector_type(4))) short bf16x4;
typedef unsigned short ushort_t;

#define QSCALE 0.18033688f   // 0.125 * log2(e): softmax runs in exp2 domain
#define DEFER_THR 8.0f       // T13 defer-max threshold (log2 units)

__device__ inline short f2bf(float f) {
  unsigned u = __builtin_bit_cast(unsigned, f);
  u += 0x7fffu + ((u >> 16) & 1u);   // RNE
  return (short)(u >> 16);
}

__device__ inline void gload_lds16(const void* g, void* l) {
  __builtin_amdgcn_global_load_lds(
      (const __attribute__((address_space(1))) void*)g,
      (__attribute__((address_space(3))) void*)l, 16, 0, 0);
}

__device__ inline unsigned cvtpk(float a, float b) {
  unsigned r;
  asm("v_cvt_pk_bf16_f32 %0, %1, %2" : "=v"(r) : "v"(a), "v"(b));
  return r;
}

// swaps: a' = [a_lo|b_lo], b' = [a_hi|b_hi]  (32-lane halves)
__device__ inline void swap32u(unsigned& a, unsigned& b) {
  asm("v_permlane32_swap_b32 %0, %1" : "+v"(a), "+v"(b));
}

// ---------------- fp32 -> bf16 convert (vectorized) ----------------
__global__ __launch_bounds__(256) void cvt_bf16(const float* __restrict__ src,
                                                short* __restrict__ dst, int n8) {
  int i = blockIdx.x * 256 + threadIdx.x;
  if (i >= n8) return;
  const float4* s = (const float4*)src;
  float4 a = s[2 * i], b = s[2 * i + 1];
  bf16x8 o;
  o[0] = f2bf(a.x); o[1] = f2bf(a.y); o[2] = f2bf(a.z); o[3] = f2bf(a.w);
  o[4] = f2bf(b.x); o[5] = f2bf(b.y); o[6] = f2bf(b.z); o[7] = f2bf(b.w);
  ((bf16x8*)dst)[i] = o;
}

// ---------------- m97-style GEMM: C[M][N] = A[M][K] * B[N][K]^T ----------------
template <int F32OUT>
__global__ __launch_bounds__(256) void gemm_bt(const short* __restrict__ A,
                                               const short* __restrict__ B,
                                               void* __restrict__ Cv,
                                               const float* __restrict__ bias,
                                               int scale_cols, float scale_val,
                                               int M, int N, int K) {
  __shared__ short As[128 * 64];
  __shared__ short Bs[128 * 64];
  const int tid = threadIdx.x, wv = tid >> 6, ln = tid & 63;
  const int wm = wv >> 1, wn = wv & 1;
  const int bm0 = blockIdx.y * 128, bn0 = blockIdx.x * 128;
  const int lrow = ln & 15, lk = (ln >> 4) * 8;
  f32x4 acc[4][4] = {};

  for (int k0 = 0; k0 < K; k0 += 64) {
    __syncthreads();
#pragma unroll
    for (int i = 0; i < 4; i++) {
      int id = i * 256 + tid;
      int row = id >> 3, col = (id & 7) * 8;
      gload_lds16(A + (size_t)(bm0 + row) * K + k0 + col,
                  (char*)As + (i * 4 + wv) * 1024);
      gload_lds16(B + (size_t)(bn0 + row) * K + k0 + col,
                  (char*)Bs + (i * 4 + wv) * 1024);
    }
    __syncthreads();
#pragma unroll
    for (int kk = 0; kk < 2; kk++) {
      bf16x8 af[4], bfr[4];
#pragma unroll
      for (int m = 0; m < 4; m++)
        af[m] = *(const bf16x8*)&As[(wm * 64 + m * 16 + lrow) * 64 + kk * 32 + lk];
#pragma unroll
      for (int n = 0; n < 4; n++)
        bfr[n] = *(const bf16x8*)&Bs[(wn * 64 + n * 16 + lrow) * 64 + kk * 32 + lk];
#pragma unroll
      for (int m = 0; m < 4; m++)
#pragma unroll
        for (int n = 0; n < 4; n++)
          acc[m][n] = __builtin_amdgcn_mfma_f32_16x16x32_bf16(af[m], bfr[n], acc[m][n], 0, 0, 0);
    }
  }

  const int r0 = bm0 + wm * 64, c0 = bn0 + wn * 64;
#pragma unroll
  for (int m = 0; m < 4; m++)
#pragma unroll
    for (int n = 0; n < 4; n++)
#pragma unroll
      for (int r = 0; r < 4; r++) {
        int row = r0 + m * 16 + (ln >> 4) * 4 + r;
        int col = c0 + n * 16 + lrow;
        float v = acc[m][n][r];
        if (col < scale_cols) v *= scale_val;
        if (F32OUT) {
          ((float*)Cv)[(size_t)row * N + col] = v + bias[col];
        } else {
          ((short*)Cv)[(size_t)row * N + col] = f2bf(v);
        }
      }
}

// ---------------- flash attention, 8-warp 32x32 swapped structure ----------------
// QKV: [B*N=4096][3072] bf16; q (pre-scaled by QSCALE) at h*64+d, k at +1024, v at +2048.
// Grid (8 qtiles, 32 bh), 512 threads. Warp owns 32 q rows; lane owns q = lane&31.
__global__ __launch_bounds__(512) void attn_fwd(const short* __restrict__ QKV,
                                                short* __restrict__ AO) {
  __shared__ short Ks[2][64 * 64];   // [kv][d], XOR-swizzled 16B blocks
  __shared__ short Vt[2][64 * 64];   // [d][kv], XOR-swizzled
  const int tid = threadIdx.x, wv = tid >> 6, ln = tid & 63;
  const int lq = ln & 31, hi = ln >> 5;
  const int qt = blockIdx.x, bh = blockIdx.y;
  const int b = bh >> 4, h = bh & 15;
  const short* base = QKV + (size_t)b * 2048 * 3072 + h * 64;
  const short* Kg = base + 1024;
  const short* Vg = base + 2048;
  const int qrow = qt * 256 + wv * 32 + lq;

  // Q fragments in registers: lane holds Q[q=lq][d = ds*16 + hi*8 + 0..7]
  bf16x8 qf[4];
  {
    const short* Qrow = base + (size_t)qrow * 3072;
#pragma unroll
    for (int ds = 0; ds < 4; ds++)
      qf[ds] = *(const bf16x8*)(Qrow + ds * 16 + hi * 8);
  }

  // K staging: global_load_lds, wave wv -> dest rows 8wv..8wv+7, pre-swizzled src
  const int krow = 8 * wv + (ln >> 3);
  const int kcol = ((ln & 7) ^ (ln >> 3)) * 8;   // shorts
  // V staging: lane -> column d=ln, wave wv -> kv rows 8wv..8wv+7
  const int vwb = ln * 128 + ((wv ^ (ln & 7)) << 4);

  float m_run = -1e30f, l_run = 0.f;
  f32x16 o0 = {}, o1 = {};
  ushort_t vu[8];

  // prologue: tile 0
  gload_lds16(Kg + (size_t)krow * 3072 + kcol, (char*)Ks[0] + wv * 1024);
#pragma unroll
  for (int i = 0; i < 8; i++)
    vu[i] = *(const ushort_t*)(Vg + (size_t)(8 * wv + i) * 3072 + ln);
  {
    bf16x8 w;
#pragma unroll
    for (int i = 0; i < 8; i++) w[i] = (short)vu[i];
    *(bf16x8*)((char*)Vt[0] + vwb) = w;
  }
  __syncthreads();

  for (int t = 0; t < 32; t++) {
    const int s = t & 1;
    if (t < 31) {  // prefetch next tile (hidden under this tile's MFMAs)
      gload_lds16(Kg + (size_t)((t + 1) * 64 + krow) * 3072 + kcol,
                  (char*)Ks[s ^ 1] + wv * 1024);
#pragma unroll
      for (int i = 0; i < 8; i++)
        vu[i] = *(const ushort_t*)(Vg + (size_t)((t + 1) * 64 + 8 * wv + i) * 3072 + ln);
    }

    // S^T = K Q^T : c0 = kv 0..31, c1 = kv 32..63; lane owns column q=lq
    f32x16 c0 = {}, c1 = {};
    const char* Kb = (const char*)Ks[s];
#pragma unroll
    for (int ds = 0; ds < 4; ds++) {
      const int cp = (ds * 2 + hi) ^ (lq & 7);
      bf16x8 ka0 = *(const bf16x8*)(Kb + lq * 128 + cp * 16);
      bf16x8 ka1 = *(const bf16x8*)(Kb + (32 + lq) * 128 + cp * 16);
      c0 = __builtin_amdgcn_mfma_f32_32x32x16_bf16(ka0, qf[ds], c0, 0, 0, 0);
      c1 = __builtin_amdgcn_mfma_f32_32x32x16_bf16(ka1, qf[ds], c1, 0, 0, 0);
    }

    // row max (in-register, log2 domain)
    float mx = c0[0];
#pragma unroll
    for (int r = 1; r < 16; r++) mx = fmaxf(mx, c0[r]);
#pragma unroll
    for (int r = 0; r < 16; r++) mx = fmaxf(mx, c1[r]);
    mx = fmaxf(mx, __shfl_xor(mx, 32));

    if (!__all((mx - m_run) <= DEFER_THR)) {   // T13 defer-max
      float mn = fmaxf(m_run, mx);
      float al = __builtin_amdgcn_exp2f(m_run - mn);
      m_run = mn;
      l_run *= al;
#pragma unroll
      for (int r = 0; r < 16; r++) { o0[r] *= al; o1[r] *= al; }
    }

    // p = exp2(s - m); sum
#pragma unroll
    for (int r = 0; r < 16; r++) c0[r] = __builtin_amdgcn_exp2f(c0[r] - m_run);
#pragma unroll
    for (int r = 0; r < 16; r++) c1[r] = __builtin_amdgcn_exp2f(c1[r] - m_run);
    float ts = 0.f;
#pragma unroll
    for (int r = 0; r < 16; r++) ts += c0[r] + c1[r];
    ts += __shfl_xor(ts, 32);
    l_run += ts;

    // T12: build P^T B-fragments in-register (cvt_pk + permlane32_swap)
    bf16x8 pa[4];
#pragma unroll
    for (int cs = 0; cs < 2; cs++) {
      const f32x16& p = cs ? c1 : c0;
#pragma unroll
      for (int ksl = 0; ksl < 2; ksl++) {
        unsigned A0 = cvtpk(p[8 * ksl + 0], p[8 * ksl + 1]);
        unsigned A1 = cvtpk(p[8 * ksl + 2], p[8 * ksl + 3]);
        unsigned B0 = cvtpk(p[8 * ksl + 4], p[8 * ksl + 5]);
        unsigned B1 = cvtpk(p[8 * ksl + 6], p[8 * ksl + 7]);
        swap32u(A0, B0);
        swap32u(A1, B1);
        union { unsigned u[4]; bf16x8 v; } tmp;
        tmp.u[0] = A0; tmp.u[1] = A1; tmp.u[2] = B0; tmp.u[3] = B1;
        pa[cs * 2 + ksl] = tmp.v;
      }
    }

    // O^T += V^T P^T : o0 = d 0..31, o1 = d 32..63; lane owns column q=lq
    const char* Vb = (const char*)Vt[s];
#pragma unroll
    for (int ks = 0; ks < 4; ks++) {
      const int cp = (ks * 2 + hi) ^ (lq & 7);
      bf16x8 va0 = *(const bf16x8*)(Vb + lq * 128 + cp * 16);
      bf16x8 va1 = *(const bf16x8*)(Vb + (32 + lq) * 128 + cp * 16);
      o0 = __builtin_amdgcn_mfma_f32_32x32x16_bf16(va0, pa[ks], o0, 0, 0, 0);
      o1 = __builtin_amdgcn_mfma_f32_32x32x16_bf16(va1, pa[ks], o1, 0, 0, 0);
    }

    if (t < 31) {  // late V write into next buffer (T14 issue-early/write-late)
      bf16x8 w;
#pragma unroll
      for (int i = 0; i < 8; i++) w[i] = (short)vu[i];
      *(bf16x8*)((char*)Vt[s ^ 1] + vwb) = w;
    }
    __syncthreads();
  }

  // epilogue: AO[b, q, h, d] = O^T[d][q] / l   (d = dt*32 + 8g + 4hi + 0..3)
  const float inv = __builtin_amdgcn_rcpf(l_run);
  short* Arow = AO + ((size_t)(b * 2048) + qrow) * 1024 + h * 64;
#pragma unroll
  for (int dt = 0; dt < 2; dt++) {
    const f32x16& o = dt ? o1 : o0;
#pragma unroll
    for (int g = 0; g < 4; g++) {
      bf16x4 w;
#pragma unroll
      for (int i = 0; i < 4; i++) w[i] = f2bf(o[4 * g + i] * inv);
      *(bf16x4*)(Arow + dt * 32 + 8 * g + 4 * hi) = w;
    }
  }
}

// ---------------- launch ----------------
extern "C" void kernel_launch(void* const* d_in, const int* in_sizes, int n_in,
                              void* d_out, int out_size, void* d_ws, size_t ws_size,
                              hipStream_t stream) {
  const float* x = (const float*)d_in[0];       // [2,2048,1024]
  const float* w_qkv = (const float*)d_in[1];   // [3072,1024]
  const float* w_proj = (const float*)d_in[2];  // [1024,1024]
  const float* b_proj = (const float*)d_in[3];  // [1024]
  float* out = (float*)d_out;                   // [2,2048,1024] fp32

  char* ws = (char*)d_ws;
  short* Xb = (short*)(ws + 0);                  //  8 MB  [4096][1024]
  short* Wq = (short*)(ws + 8388608);            //  6 MB  [3072][1024]
  short* Wp = (short*)(ws + 14680064);           //  2 MB  [1024][1024]
  short* QKV = (short*)(ws + 16777216);          // 24 MB  [4096][3072]
  short* AO = (short*)(ws + 41943040);           //  8 MB  [4096][1024]

  cvt_bf16<<<2048, 256, 0, stream>>>(x, Xb, 4096 * 1024 / 8);
  cvt_bf16<<<1536, 256, 0, stream>>>(w_qkv, Wq, 3072 * 1024 / 8);
  cvt_bf16<<<512, 256, 0, stream>>>(w_proj, Wp, 1024 * 1024 / 8);

  // q columns (<1024) pre-scaled by 0.125*log2e for exp2-domain softmax
  gemm_bt<0><<<dim3(24, 32), 256, 0, stream>>>(Xb, Wq, (void*)QKV, nullptr,
                                               1024, QSCALE, 4096, 3072, 1024);

  attn_fwd<<<dim3(8, 32), 512, 0, stream>>>(QKV, AO);

  gemm_bt<1><<<dim3(8, 32), 256, 0, stream>>>(AO, Wp, (void*)out, b_proj,
                                              0, 1.0f, 4096, 1024, 1024);
}